// Round 7
// baseline (351.646 us; speedup 1.0000x reference)
//
#include <hip/hip_runtime.h>
#include <hip/hip_bf16.h>
#include <stdint.h>

#define TSTEPS 4

typedef __bf16 bf16_t;
typedef __attribute__((ext_vector_type(8))) __bf16 bf16x8;
typedef __attribute__((ext_vector_type(16))) float f32x16;
typedef __attribute__((ext_vector_type(4))) unsigned short ushort4v;

union frag_u { bf16x8 v; uint32_t d[4]; unsigned short u[8]; };

// gfx9 s_waitcnt imm: vm [3:0]|[15:14]; exp [6:4]; lgkm [11:8].
#define WT_VM9_LG0 0x079    // vmcnt(9)  lgkmcnt(0)
#define WT_VM8     0xF78    // vmcnt(8)
#define WT_LG0     0xC07F   // lgkmcnt(0), vm unbounded
#define WT_VM0_LG0 0x070    // full drain (tail)

// ---------------------------------------------------------------------------
// R23: 128x128 block tile, 16 waves (1024 thr), wave tile 32x32.
// Model (fits R16-R22): bound = L2->CU BW ~60 B/cyc/CU. bytes per matrix-cyc
// = 31.7*(32/BM+32/BN): 64x64 -> 127 B/cyc demand (ceiling 47%, measured
// 42-50% across 4 structures); 128x128 -> 62 B/cyc (ceiling ~95%).
// Block tile grows, wave tile stays 32x32 (acc=64 VGPR; R20's failure was
// growing the WAVE tile -> 128 acc VGPR -> occupancy death).
// B: LDS-staged, 2-kb phases, dbuf (8KB/kb; 16 chunks of 1KB per phase =
// one global_load_lds per wave). A: byte-spikes, register-prefetched one
// phase ahead (8 loads/phase; L1-dedup x4 waves sharing m_blk).
// One barrier per phase; counted waits vmcnt(9)/lgkm(0)/vmcnt(8).
// Spike bytes 0x3F -> v_perm high-byte = bf16 0.5; B pre-doubled (exact
// exponent bump) so products are bitwise 1.0*w (R19/R21/R22-proven).
// A layout: [m_blk32][kb16][t][row0..31][16 bytes], byte = 0x00 / 0x3F.
// B-frag layout: packet ((n>>5)*NKB + (k>>4))*512 + ((n&31)+32*((k>>3)&1))*8
// + (k&7), bf16, value = 2*w_hi / 2*w_lo.
// ---------------------------------------------------------------------------

// ---------------------------------------------------------------------------
// Stage 1: input LIF encoder -> spike 0x3F bytes. C=128. XLA-exact LIF.
// ---------------------------------------------------------------------------
__global__ void spike_encode_i8(const float* __restrict__ x,
                                uint4* __restrict__ s1)
{
    const int C = 128;
    int tid = blockIdx.x * blockDim.x + threadIdx.x;  // 65536 = 256*8*32
    int row = tid & 31;
    int kb  = (tid >> 5) & 7;
    int m_blk = tid >> 8;
    int m = m_blk * 32 + row;
    const float* px = x + (size_t)m * C + kb * 16;
    float xv[16];
#pragma unroll
    for (int j = 0; j < 16; j += 4) {
        float4 t4 = *(const float4*)(px + j);
        xv[j] = t4.x; xv[j+1] = t4.y; xv[j+2] = t4.z; xv[j+3] = t4.w;
    }
    float v[16];
#pragma unroll
    for (int j = 0; j < 16; ++j) v[j] = 0.0f;
#pragma unroll
    for (int t = 0; t < TSTEPS; ++t) {
        uint32_t dw[4] = {0u, 0u, 0u, 0u};
#pragma unroll
        for (int j = 0; j < 16; ++j) {
            float vv = __fadd_rn(v[j], __fmul_rn(__fsub_rn(xv[j], v[j]), 0.5f));
            bool sp = (vv >= 1.0f);
            dw[j >> 2] |= sp ? (0x3Fu << ((j & 3) * 8)) : 0u;
            v[j] = sp ? 0.0f : vv;
        }
        uint4 o; o.x = dw[0]; o.y = dw[1]; o.z = dw[2]; o.w = dw[3];
        s1[((size_t)(m_blk * 8 + kb) * 4 + t) * 32 + row] = o;
    }
}

// ---------------------------------------------------------------------------
// Weight prep: W [K][N] fp32 -> 2*hi / 2*lo bf16 split in B-frag layout.
// ---------------------------------------------------------------------------
__global__ void split_transpose_all(const float* __restrict__ enc_W,
                                    const float* __restrict__ W_cells,
                                    bf16_t* __restrict__ W1h, bf16_t* __restrict__ W1l,
                                    bf16_t* __restrict__ W2h, bf16_t* __restrict__ W2l,
                                    bf16_t* __restrict__ W3h, bf16_t* __restrict__ W3l)
{
    const int N = 1024;
    const float* W;
    bf16_t *hi, *lo;
    int K;
    if (blockIdx.z == 0) {
        if (blockIdx.x >= 4) return;
        W = enc_W; hi = W1h; lo = W1l; K = 128;
    } else if (blockIdx.z == 1) {
        W = W_cells; hi = W2h; lo = W2l; K = 1024;
    } else {
        W = W_cells + (size_t)1024 * 1024; hi = W3h; lo = W3l; K = 1024;
    }
    const int NKB = K >> 4;
    __shared__ float tile[32][33];
    int k0 = blockIdx.x * 32, n0 = blockIdx.y * 32;
    int tx = threadIdx.x & 31, ty = threadIdx.x >> 5;
    for (int kk = ty; kk < 32; kk += 8)
        tile[kk][tx] = W[(size_t)(k0 + kk) * N + n0 + tx];
    __syncthreads();

    const int nn = tx;
    const int oc = ty;            // 0..7
    const int o2 = oc & 3;        // k-octet
    const bool isLo = (oc >> 2) != 0;
    const int kblk = (k0 >> 4) + (o2 >> 1);
    const int lane_in_packet = nn + 32 * (o2 & 1);

    frag_u f;
#pragma unroll
    for (int j = 0; j < 8; ++j) {
        float wv = tile[o2 * 8 + j][nn];
        bf16_t h = (bf16_t)wv;                          // original hi rounding
        bf16_t l = (bf16_t)(wv - (float)h);             // original lo rounding
        f.v[j] = isLo ? (bf16_t)(2.0f * (float)l)       // exact doubling
                      : (bf16_t)(2.0f * (float)h);
    }
    bf16_t* dst = (isLo ? lo : hi)
        + ((size_t)((n0 + nn) >> 5) * NKB + kblk) * 512 + lane_in_packet * 8;
    *(bf16x8*)dst = f.v;
}

// ---------------------------------------------------------------------------
// Fused MFMA GEMM + multistep LIF. R23: 128x128 tile, 16 waves, LDS B
// (2-kb phases, dbuf), reg-prefetched A, one barrier/phase, counted waits.
// ---------------------------------------------------------------------------
template <int K, bool LAST>
__global__ __launch_bounds__(1024, 4)
void gemm_lif_mfma(const uint8_t* __restrict__ Abytes,
                   const bf16_t* __restrict__ Bh,
                   const bf16_t* __restrict__ Bl,
                   const float* __restrict__ bias,
                   uint8_t* __restrict__ Sbytes,
                   float* __restrict__ Out,
                   int M, int N)
{
    constexpr int NKB = K >> 4;                 // 8 or 64
    constexpr int NP  = NKB >> 1;               // 2-kb pairs (even)
    __shared__ __align__(16) uint8_t ldsB[2][2][8192];   // [buf][kbip][8KB]
    __shared__ __align__(8) unsigned short sh[16][256];  // epilogue, per-wave

    const int tid = threadIdx.x;
    const int lane = tid & 63;
    const int wid = tid >> 6;                   // 0..15
    const int l31 = lane & 31;
    const int half = lane >> 5;

    // XCD-locality swizzle: 512 blocks. XCD x owns m_t in [x*8, x*8+8);
    // walk nh(2) x mloc(8) x n4(4). Hot set per XCD ~ A-tile 512KB +
    // 4 B-panels 2MB < 4MB L2. Bijective.
    const int bid = blockIdx.x;
    const int xcd = bid & 7;
    const int j   = bid >> 3;                   // 0..63
    const int nh   = j >> 5;                    // 0..1
    const int r    = j & 31;
    const int mloc = r >> 2;                    // 0..7
    const int n_t  = nh * 4 + (r & 3);          // 0..7
    const int m_t  = xcd * 8 + mloc;            // 0..63

    const int m0 = m_t * 128, n0 = n_t * 128;
    const int wave_m = (wid & 3) * 32;
    const int wave_n = (wid >> 2) * 32;
    const int m_blk = (m0 + wave_m) >> 5;

    const uint8_t* pA = Abytes + (size_t)m_blk * NKB * 4 * 512 + l31 * 16 + half * 8;

    // B staging: 16 chunks of 1KB per phase (2 kb x 8KB). Wave wid stages
    // chunk: kbip = wid>>3, c = wid&7 -> plane = c&1, n_blk_local = c>>1.
    const int kbip = wid >> 3;
    const int cch  = wid & 7;
    const uint8_t* stage_src = (const uint8_t*)(((cch & 1) ? Bl : Bh)
        + (size_t)((n0 >> 5) + (cch >> 1)) * NKB * 512)
        + (size_t)kbip * 1024 + (lane << 4);
    uint8_t* stage_dst = &ldsB[0][0][0] + kbip * 8192 + cch * 1024;
    // Consumer: wave wid reads n_blk_local = wid>>2: hi at +0, lo at +1024.
    const uint8_t* ldsRd = &ldsB[0][0][0] + ((wid >> 2) << 11) + (lane << 4);

    f32x16 acc[TSTEPS];
#pragma unroll
    for (int t = 0; t < TSTEPS; ++t)
        for (int rr = 0; rr < 16; ++rr) acc[t][rr] = 0.0f;

    uint2 fm[2][2][4];    // [pair-slot][kb-in-pair][t]

#define STAGE(pair_, b_)                                                      \
    __builtin_amdgcn_global_load_lds(                                         \
        (const __attribute__((address_space(1))) uint32_t*)                   \
            (stage_src + (size_t)(pair_) * 2048),                             \
        (__attribute__((address_space(3))) uint32_t*)                         \
            (stage_dst + (b_) * 16384),                                       \
        16, 0, 0);

#define LOADA2(pair_, s_) {                                                  \
        fm[s_][0][0] = *(const uint2*)(pA + ((size_t)(pair_)*8 + 0) * 512);  \
        fm[s_][0][1] = *(const uint2*)(pA + ((size_t)(pair_)*8 + 1) * 512);  \
        fm[s_][0][2] = *(const uint2*)(pA + ((size_t)(pair_)*8 + 2) * 512);  \
        fm[s_][0][3] = *(const uint2*)(pA + ((size_t)(pair_)*8 + 3) * 512);  \
        fm[s_][1][0] = *(const uint2*)(pA + ((size_t)(pair_)*8 + 4) * 512);  \
        fm[s_][1][1] = *(const uint2*)(pA + ((size_t)(pair_)*8 + 5) * 512);  \
        fm[s_][1][2] = *(const uint2*)(pA + ((size_t)(pair_)*8 + 6) * 512);  \
        fm[s_][1][3] = *(const uint2*)(pA + ((size_t)(pair_)*8 + 7) * 512);  \
    }

// byte 0x3F -> high byte of each 16-bit half = 0x3F00 = bf16 0.5 (1 perm/dw)
#define EXPANDF(a_, f_) {                                                    \
        (f_).d[0] = __builtin_amdgcn_perm((a_).x, 0u, 0x05000400u);          \
        (f_).d[1] = __builtin_amdgcn_perm((a_).x, 0u, 0x07000600u);          \
        (f_).d[2] = __builtin_amdgcn_perm((a_).y, 0u, 0x05000400u);          \
        (f_).d[3] = __builtin_amdgcn_perm((a_).y, 0u, 0x07000600u);          \
    }

#define MFMAS(s_, kbip_, fhv_, flv_) {                                       \
        frag_u af0, af1, af2, af3;                                           \
        EXPANDF(fm[s_][kbip_][0], af0);                                      \
        EXPANDF(fm[s_][kbip_][1], af1);                                      \
        EXPANDF(fm[s_][kbip_][2], af2);                                      \
        EXPANDF(fm[s_][kbip_][3], af3);                                      \
        acc[0] = __builtin_amdgcn_mfma_f32_32x32x16_bf16(af0.v, fhv_, acc[0], 0, 0, 0); \
        acc[1] = __builtin_amdgcn_mfma_f32_32x32x16_bf16(af1.v, fhv_, acc[1], 0, 0, 0); \
        acc[2] = __builtin_amdgcn_mfma_f32_32x32x16_bf16(af2.v, fhv_, acc[2], 0, 0, 0); \
        acc[3] = __builtin_amdgcn_mfma_f32_32x32x16_bf16(af3.v, fhv_, acc[3], 0, 0, 0); \
        acc[0] = __builtin_amdgcn_mfma_f32_32x32x16_bf16(af0.v, flv_, acc[0], 0, 0, 0); \
        acc[1] = __builtin_amdgcn_mfma_f32_32x32x16_bf16(af1.v, flv_, acc[1], 0, 0, 0); \
        acc[2] = __builtin_amdgcn_mfma_f32_32x32x16_bf16(af2.v, flv_, acc[2], 0, 0, 0); \
        acc[3] = __builtin_amdgcn_mfma_f32_32x32x16_bf16(af3.v, flv_, acc[3], 0, 0, 0); \
    }

// Phase for pair_ in buf b_: stage+loadA pair_+1 into b_^1, compute 2 kb.
// vmcnt(9)+lgkm(0): 9 outstanding = this phase's (1 stage + 8 A) -> prior
// phase's A(pair_) loads are drained. vmcnt(8): youngest 8 = this phase's A
// -> this phase's stage has landed; barrier publishes it to all waves.
#define PHASE(pair_, b_) {                                                   \
        STAGE((pair_) + 1, (b_) ^ 1);                                        \
        LOADA2((pair_) + 1, (b_) ^ 1);                                       \
        bf16x8 fh0 = *(const bf16x8*)(ldsRd + (b_) * 16384);                 \
        bf16x8 fl0 = *(const bf16x8*)(ldsRd + (b_) * 16384 + 1024);          \
        __builtin_amdgcn_s_waitcnt(WT_VM9_LG0);                              \
        asm volatile("" ::: "memory");                                       \
        MFMAS(b_, 0, fh0, fl0);                                              \
        bf16x8 fh1 = *(const bf16x8*)(ldsRd + (b_) * 16384 + 8192);          \
        bf16x8 fl1 = *(const bf16x8*)(ldsRd + (b_) * 16384 + 8192 + 1024);   \
        __builtin_amdgcn_s_waitcnt(WT_LG0);                                  \
        asm volatile("" ::: "memory");                                       \
        MFMAS(b_, 1, fh1, fl1);                                              \
        __builtin_amdgcn_s_waitcnt(WT_VM8);                                  \
        asm volatile("" ::: "memory");                                       \
        __builtin_amdgcn_s_barrier();                                        \
        asm volatile("" ::: "memory");                                       \
    }

    // Prologue: stage pair 0 into buf0, A(pair0) into slot0.
    STAGE(0, 0);
    LOADA2(0, 0);
    __builtin_amdgcn_s_waitcnt(WT_VM8);   // stage(0) landed (8 A younger)
    asm volatile("" ::: "memory");
    __builtin_amdgcn_s_barrier();
    asm volatile("" ::: "memory");

    for (int p = 0; p < NP - 2; p += 2) {
        PHASE(p + 0, 0);
        PHASE(p + 1, 1);
    }
    PHASE(NP - 2, 0);                     // stages+loads pair NP-1
    {   // tail: pair NP-1 in buf 1 — nothing left to issue
        bf16x8 fh0 = *(const bf16x8*)(ldsRd + 16384);
        bf16x8 fl0 = *(const bf16x8*)(ldsRd + 16384 + 1024);
        __builtin_amdgcn_s_waitcnt(WT_VM0_LG0);
        asm volatile("" ::: "memory");
        MFMAS(1, 0, fh0, fl0);
        bf16x8 fh1 = *(const bf16x8*)(ldsRd + 16384 + 8192);
        bf16x8 fl1 = *(const bf16x8*)(ldsRd + 16384 + 8192 + 1024);
        __builtin_amdgcn_s_waitcnt(WT_LG0);
        asm volatile("" ::: "memory");
        MFMAS(1, 1, fh1, fl1);
    }

#undef PHASE
#undef MFMAS
#undef EXPANDF
#undef LOADA2
#undef STAGE

    // --- LIF epilogue: t-scan in registers (XLA-exact arithmetic) ---
    const float bv = bias[n0 + wave_n + l31];
    f32x16 vmem;
#pragma unroll
    for (int rr = 0; rr < 16; ++rr) vmem[rr] = 0.0f;
    uint64_t bits = 0ull;
    unsigned short* myt = &sh[wid][0];          // [row][kb][t] = [32][2][4]

    const int NKBo = N >> 4;
    const int kbase = (n0 + wave_n) >> 4;

    for (int t = 0; t < TSTEPS; ++t) {
#pragma unroll
        for (int rr = 0; rr < 16; ++rr) {
            float y = __fadd_rn(acc[t][rr], bv);
            float vv = vmem[rr];
            vv = __fadd_rn(vv, __fmul_rn(__fsub_rn(y, vv), 0.5f));
            bool sp = (vv >= 1.0f);
            vmem[rr] = sp ? 0.0f : vv;
            if (LAST) {
                bits |= sp ? (1ull << (rr * 4 + t)) : 0ull;
            } else {
                unsigned long long b = __ballot(sp);
                if (l31 == 0) {
                    uint32_t hb = (uint32_t)(b >> (half * 32));
                    int rowi = (rr & 3) + 8 * (rr >> 2) + 4 * half;
                    myt[(rowi * 2 + 0) * 4 + t] = (unsigned short)hb;
                    myt[(rowi * 2 + 1) * 4 + t] = (unsigned short)(hb >> 16);
                }
            }
        }
    }

    if (LAST) {
#pragma unroll
        for (int rr = 0; rr < 16; ++rr) {
            int m_r = (rr & 3) + 8 * (rr >> 2) + 4 * half;
            int m = m0 + wave_m + m_r;
            int n = n0 + wave_n + l31;
            int cnt = __popc((unsigned)((bits >> (rr * 4)) & 0xFull));
            Out[(size_t)m * N + n] = 0.25f * (float)cnt;
        }
    } else {
        // Emit next-stage A bytes: 0x00 / 0x3F.
        const ushort4v pk = *(const ushort4v*)&myt[(l31 * 2 + half) * 4];
#pragma unroll
        for (int t = 0; t < TSTEPS; ++t) {
            uint32_t m16 = pk[t];
            uint4 o;
            o.x = (((m16      ) & 0xFu) * 0x00204081u & 0x01010101u) * 0x3Fu;
            o.y = (((m16 >>  4) & 0xFu) * 0x00204081u & 0x01010101u) * 0x3Fu;
            o.z = (((m16 >>  8) & 0xFu) * 0x00204081u & 0x01010101u) * 0x3Fu;
            o.w = (((m16 >> 12) & 0xFu) * 0x00204081u & 0x01010101u) * 0x3Fu;
            *(uint4*)(Sbytes + ((((size_t)m_blk * NKBo + kbase + half) * 4 + t)
                                * 32 + l31) * 16) = o;
        }
    }
}

// ---------------------------------------------------------------------------
// Zero out2 (graph-capture-safe replacement for hipMemsetAsync).
// ---------------------------------------------------------------------------
__global__ void zero_out2(float* __restrict__ out2, int n)
{
    int i = blockIdx.x * blockDim.x + threadIdx.x;
    if (i < n) out2[i] = 0.0f;
}

// ---------------------------------------------------------------------------
// out2[b][d] += partial sums over L (8 chunks of 64, atomic, EXACT).
// ---------------------------------------------------------------------------
__global__ void mean_over_L_atomic(const float* __restrict__ out,
                                   float* __restrict__ out2,
                                   int B, int L, int D)
{
    int id = blockIdx.x * blockDim.x + threadIdx.x;   // B*D*8
    int bd = id & (B * D - 1);
    int chunk = id >> 14;                             // B*D = 16384 = 2^14
    int b = bd >> 10, d = bd & (D - 1);               // D = 1024
    const float* p = out + (size_t)b * L * D + (size_t)chunk * 64 * D + d;
    float s = 0.0f;
#pragma unroll 8
    for (int l = 0; l < 64; ++l) s += p[(size_t)l * D];
    atomicAdd(out2 + bd, s * (1.0f / 512.0f));
}

// ---------------------------------------------------------------------------
extern "C" void kernel_launch(void* const* d_in, const int* in_sizes, int n_in,
                              void* d_out, int out_size, void* d_ws, size_t ws_size,
                              hipStream_t stream)
{
    const float* inputs  = (const float*)d_in[0];  // [16,512,128]
    const float* enc_W   = (const float*)d_in[1];  // [128,1024]
    const float* enc_b   = (const float*)d_in[2];  // [1024]
    const float* W_cells = (const float*)d_in[3];  // [2,1024,1024]
    const float* b_cells = (const float*)d_in[4];  // [2,1024]

    const int B = 16, L = 512, C = 128, D = 1024;
    const int M = B * L;  // 8192

    // ws: s1 i8 4MB | W1h/l 0.5MB | W2h/l 4MB | W3h/l 4MB | h0 32MB | h1 32MB
    char* ws = (char*)d_ws;
    size_t off = 0;
    uint8_t* s1 = (uint8_t*)(ws + off);
    off += (size_t)(M / 32) * (C / 16) * 4 * 32 * 16;
    bf16_t* W1h = (bf16_t*)(ws + off); off += (size_t)C * D * 2;
    bf16_t* W1l = (bf16_t*)(ws + off); off += (size_t)C * D * 2;
    bf16_t* W2h = (bf16_t*)(ws + off); off += (size_t)D * D * 2;
    bf16_t* W2l = (bf16_t*)(ws + off); off += (size_t)D * D * 2;
    bf16_t* W3h = (bf16_t*)(ws + off); off += (size_t)D * D * 2;
    bf16_t* W3l = (bf16_t*)(ws + off); off += (size_t)D * D * 2;
    uint8_t* h0 = (uint8_t*)(ws + off);
    off += (size_t)(M / 32) * (D / 16) * 4 * 32 * 16;
    uint8_t* h1 = (uint8_t*)(ws + off);

    float* out  = (float*)d_out;          // [M, D]
    float* out2 = out + (size_t)M * D;    // [B, D]

    split_transpose_all<<<dim3(32, 32, 3), 256, 0, stream>>>(
        enc_W, W_cells, W1h, W1l, W2h, W2l, W3h, W3l);

    spike_encode_i8<<<256, 256, 0, stream>>>(inputs, (uint4*)s1);

    zero_out2<<<(B * D + 255) / 256, 256, 0, stream>>>(out2, B * D);

    const int nblocks = (M / 128) * (D / 128);   // 512
    gemm_lif_mfma<128, false><<<nblocks, 1024, 0, stream>>>(
        s1, W1h, W1l, enc_b, h0, nullptr, M, D);
    gemm_lif_mfma<1024, false><<<nblocks, 1024, 0, stream>>>(
        h0, W2h, W2l, b_cells, h1, nullptr, M, D);
    gemm_lif_mfma<1024, true><<<nblocks, 1024, 0, stream>>>(
        h1, W3h, W3l, b_cells + D, nullptr, out, M, D);

    mean_over_L_atomic<<<(B * D * 8) / 256, 256, 0, stream>>>(
        out, out2, B, L, D);
}

// Round 8
// 315.646 us; speedup vs baseline: 1.1141x; 1.1141x over previous
//
#include <hip/hip_runtime.h>
#include <hip/hip_bf16.h>
#include <stdint.h>

#define TSTEPS 4

typedef __bf16 bf16_t;
typedef __attribute__((ext_vector_type(8))) __bf16 bf16x8;
typedef __attribute__((ext_vector_type(16))) float f32x16;
typedef __attribute__((ext_vector_type(4))) unsigned short ushort4v;

union frag_u { bf16x8 v; uint32_t d[4]; unsigned short u[8]; };

// gfx9 s_waitcnt imm: vm [3:0]|[15:14]; exp [6:4]; lgkm [11:8].
#define WT_VM5_LG0  0x075   // vmcnt(5)  lgkmcnt(0)
#define WT_VM4      0xF74   // vmcnt(4)
#define WT_VM0_LG0  0x070   // full drain (tail)

// ---------------------------------------------------------------------------
// R24 = R22 base (LDS-staged B, 2-phase counted waits, 118.5us) + 3 changes:
//  (1) s_setprio(1) around the 8-MFMA burst (T5; R22's stage/compute phases
//      give the wave role-diversity T5 needs, unlike lockstep nulls),
//  (2) B-fragment ds_reads hoisted across the barrier into the previous step
//      (removes ~120cy exposed LDS latency from the lgkm(0) critical path),
//  (3) mean-over-L fused into the LAST epilogue (exact: all terms multiples
//      of 2^-11, order-independent) -> standalone 33MB-reread kernel deleted.
// Model status: L2/L1 bandwidth ceilings REFUTED both ways (R22 null, R23
// worse at half the bytes; R17 worse at 2x). Plateau = latency/stall
// equilibrium; this round attacks scheduler arbitration + LDS latency.
// Spike bytes 0x3F -> v_perm high-byte = bf16 0.5; B pre-doubled (exact
// exponent bump) so products are bitwise 1.0*w (R19/R21/R22-proven).
// A layout: [m_blk32][kb16][t][row0..31][16 bytes], byte = 0x00 / 0x3F.
// B-frag layout: packet ((n>>5)*NKB + (k>>4))*512 + ((n&31)+32*((k>>3)&1))*8
// + (k&7), bf16, value = 2*w_hi / 2*w_lo.
// ---------------------------------------------------------------------------

// ---------------------------------------------------------------------------
// Stage 1: input LIF encoder -> spike 0x3F bytes. C=128. XLA-exact LIF.
// ---------------------------------------------------------------------------
__global__ void spike_encode_i8(const float* __restrict__ x,
                                uint4* __restrict__ s1)
{
    const int C = 128;
    int tid = blockIdx.x * blockDim.x + threadIdx.x;  // 65536 = 256*8*32
    int row = tid & 31;
    int kb  = (tid >> 5) & 7;
    int m_blk = tid >> 8;
    int m = m_blk * 32 + row;
    const float* px = x + (size_t)m * C + kb * 16;
    float xv[16];
#pragma unroll
    for (int j = 0; j < 16; j += 4) {
        float4 t4 = *(const float4*)(px + j);
        xv[j] = t4.x; xv[j+1] = t4.y; xv[j+2] = t4.z; xv[j+3] = t4.w;
    }
    float v[16];
#pragma unroll
    for (int j = 0; j < 16; ++j) v[j] = 0.0f;
#pragma unroll
    for (int t = 0; t < TSTEPS; ++t) {
        uint32_t dw[4] = {0u, 0u, 0u, 0u};
#pragma unroll
        for (int j = 0; j < 16; ++j) {
            float vv = __fadd_rn(v[j], __fmul_rn(__fsub_rn(xv[j], v[j]), 0.5f));
            bool sp = (vv >= 1.0f);
            dw[j >> 2] |= sp ? (0x3Fu << ((j & 3) * 8)) : 0u;
            v[j] = sp ? 0.0f : vv;
        }
        uint4 o; o.x = dw[0]; o.y = dw[1]; o.z = dw[2]; o.w = dw[3];
        s1[((size_t)(m_blk * 8 + kb) * 4 + t) * 32 + row] = o;
    }
}

// ---------------------------------------------------------------------------
// Weight prep: W [K][N] fp32 -> 2*hi / 2*lo bf16 split in B-frag layout.
// ---------------------------------------------------------------------------
__global__ void split_transpose_all(const float* __restrict__ enc_W,
                                    const float* __restrict__ W_cells,
                                    bf16_t* __restrict__ W1h, bf16_t* __restrict__ W1l,
                                    bf16_t* __restrict__ W2h, bf16_t* __restrict__ W2l,
                                    bf16_t* __restrict__ W3h, bf16_t* __restrict__ W3l)
{
    const int N = 1024;
    const float* W;
    bf16_t *hi, *lo;
    int K;
    if (blockIdx.z == 0) {
        if (blockIdx.x >= 4) return;
        W = enc_W; hi = W1h; lo = W1l; K = 128;
    } else if (blockIdx.z == 1) {
        W = W_cells; hi = W2h; lo = W2l; K = 1024;
    } else {
        W = W_cells + (size_t)1024 * 1024; hi = W3h; lo = W3l; K = 1024;
    }
    const int NKB = K >> 4;
    __shared__ float tile[32][33];
    int k0 = blockIdx.x * 32, n0 = blockIdx.y * 32;
    int tx = threadIdx.x & 31, ty = threadIdx.x >> 5;
    for (int kk = ty; kk < 32; kk += 8)
        tile[kk][tx] = W[(size_t)(k0 + kk) * N + n0 + tx];
    __syncthreads();

    const int nn = tx;
    const int oc = ty;            // 0..7
    const int o2 = oc & 3;        // k-octet
    const bool isLo = (oc >> 2) != 0;
    const int kblk = (k0 >> 4) + (o2 >> 1);
    const int lane_in_packet = nn + 32 * (o2 & 1);

    frag_u f;
#pragma unroll
    for (int j = 0; j < 8; ++j) {
        float wv = tile[o2 * 8 + j][nn];
        bf16_t h = (bf16_t)wv;                          // original hi rounding
        bf16_t l = (bf16_t)(wv - (float)h);             // original lo rounding
        f.v[j] = isLo ? (bf16_t)(2.0f * (float)l)       // exact doubling
                      : (bf16_t)(2.0f * (float)h);
    }
    bf16_t* dst = (isLo ? lo : hi)
        + ((size_t)((n0 + nn) >> 5) * NKB + kblk) * 512 + lane_in_packet * 8;
    *(bf16x8*)dst = f.v;
}

// ---------------------------------------------------------------------------
// Fused MFMA GEMM + multistep LIF. R24: LDS-staged B + setprio(MFMA) +
// hoisted frag reads + fused mean (LAST).
// ---------------------------------------------------------------------------
template <int K, bool LAST>
__global__ __launch_bounds__(256, 4)
void gemm_lif_mfma(const uint8_t* __restrict__ Abytes,
                   const bf16_t* __restrict__ Bh,
                   const bf16_t* __restrict__ Bl,
                   const float* __restrict__ bias,
                   uint8_t* __restrict__ Sbytes,
                   float* __restrict__ Out,
                   int M, int N)
{
    constexpr int NKB = K >> 4;                 // 8 or 64 (even)
    __shared__ __align__(16) uint8_t ldsB[2][4096];      // dbuf B kb-slab
    __shared__ __align__(8) unsigned short sh[4][256];   // epilogue, per-wave

    const int tid = threadIdx.x;
    const int lane = tid & 63;
    const int wid = tid >> 6;
    const int l31 = lane & 31;
    const int half = lane >> 5;

    // XCD-locality swizzle (R18): XCD x owns m_t in [x*16, x*16+16);
    // walk nh(2) x mloc(16) x n8(8). Bijective.
    const int bid = blockIdx.x;
    const int xcd = bid & 7;
    const int j   = bid >> 3;                   // 0..255
    const int nh   = j >> 7;                    // 0..1
    const int r    = j & 127;
    const int mloc = r >> 3;                    // 0..15
    const int n_t  = nh * 8 + (r & 7);          // 0..15
    const int m_t  = xcd * 16 + mloc;           // 0..127

    const int m0 = m_t * 64, n0 = n_t * 64;
    const int wave_m = (wid & 1) * 32;
    const int wave_n = (wid >> 1) * 32;
    const int m_blk = (m0 + wave_m) >> 5;
    const int n_blk = (n0 + wave_n) >> 5;
    (void)n_blk;

    const uint8_t* pA = Abytes + (size_t)m_blk * NKB * 4 * 512 + l31 * 16 + half * 8;

    // B staging: wave wid stages chunk wid = (n_local = wid>>1, plane = wid&1)
    // at LDS offset wid*1024. Source is the 1KB lane-linear packet.
    const uint8_t* stage_src = (const uint8_t*)(((wid & 1) ? Bl : Bh)
        + (size_t)((n0 >> 5) + (wid >> 1)) * NKB * 512) + (lane << 4);
    // Consumer: wave wid reads n_local = wid>>1: hi at +0, lo at +1024.
    const uint8_t* ldsRd = &ldsB[0][0] + ((wid >> 1) << 11) + (lane << 4);

    f32x16 acc[TSTEPS];
#pragma unroll
    for (int t = 0; t < TSTEPS; ++t)
        for (int rr = 0; rr < 16; ++rr) acc[t][rr] = 0.0f;

    uint2 fm[2][4];

#define STAGE(kb_, b_)                                                        \
    __builtin_amdgcn_global_load_lds(                                         \
        (const __attribute__((address_space(1))) uint32_t*)                   \
            (stage_src + (size_t)(kb_) * 1024),                               \
        (__attribute__((address_space(3))) uint32_t*)(&ldsB[b_][wid << 10]),  \
        16, 0, 0);

#define LOADA(kb_, s_) {                                                     \
        fm[s_][0] = *(const uint2*)(pA + ((size_t)(kb_) * 4 + 0) * 512);     \
        fm[s_][1] = *(const uint2*)(pA + ((size_t)(kb_) * 4 + 1) * 512);     \
        fm[s_][2] = *(const uint2*)(pA + ((size_t)(kb_) * 4 + 2) * 512);     \
        fm[s_][3] = *(const uint2*)(pA + ((size_t)(kb_) * 4 + 3) * 512);     \
    }

// byte 0x3F -> high byte of each 16-bit half = 0x3F00 = bf16 0.5 (1 perm/dw)
#define EXPANDF(a_, f_) {                                                    \
        (f_).d[0] = __builtin_amdgcn_perm((a_).x, 0u, 0x05000400u);          \
        (f_).d[1] = __builtin_amdgcn_perm((a_).x, 0u, 0x07000600u);          \
        (f_).d[2] = __builtin_amdgcn_perm((a_).y, 0u, 0x05000400u);          \
        (f_).d[3] = __builtin_amdgcn_perm((a_).y, 0u, 0x07000600u);          \
    }

#define MFMAS(s_, fhv_, flv_) {                                              \
        frag_u af0, af1, af2, af3;                                           \
        EXPANDF(fm[s_][0], af0);                                             \
        EXPANDF(fm[s_][1], af1);                                             \
        EXPANDF(fm[s_][2], af2);                                             \
        EXPANDF(fm[s_][3], af3);                                             \
        acc[0] = __builtin_amdgcn_mfma_f32_32x32x16_bf16(af0.v, fhv_, acc[0], 0, 0, 0); \
        acc[1] = __builtin_amdgcn_mfma_f32_32x32x16_bf16(af1.v, fhv_, acc[1], 0, 0, 0); \
        acc[2] = __builtin_amdgcn_mfma_f32_32x32x16_bf16(af2.v, fhv_, acc[2], 0, 0, 0); \
        acc[3] = __builtin_amdgcn_mfma_f32_32x32x16_bf16(af3.v, fhv_, acc[3], 0, 0, 0); \
        acc[0] = __builtin_amdgcn_mfma_f32_32x32x16_bf16(af0.v, flv_, acc[0], 0, 0, 0); \
        acc[1] = __builtin_amdgcn_mfma_f32_32x32x16_bf16(af1.v, flv_, acc[1], 0, 0, 0); \
        acc[2] = __builtin_amdgcn_mfma_f32_32x32x16_bf16(af2.v, flv_, acc[2], 0, 0, 0); \
        acc[3] = __builtin_amdgcn_mfma_f32_32x32x16_bf16(af3.v, flv_, acc[3], 0, 0, 0); \
    }

// Step kb_ (parity p_): frags for kb_ are already in cfh/cfl (read at the
// end of the previous step, after the barrier that published buf p_).
// vmcnt(5)+lgkm(0): 5 outstanding = this step's (1 stage + 4 A) -> A(kb_)
// drained; lgkm(0) drains the hoisted frag reads. vmcnt(4) before barrier:
// stage(kb_+1) landed. After the barrier, read frags for kb_+1 (buf p_^1)
// — legal: that barrier published them; buf p_^1 is not overwritten until
// STAGE in step kb_+2, which is after the next barrier.
#define STEP(kb_, p_) {                                                      \
        STAGE((kb_) + 1, (p_) ^ 1);                                          \
        LOADA((kb_) + 1, (p_) ^ 1);                                          \
        __builtin_amdgcn_s_waitcnt(WT_VM5_LG0);                              \
        asm volatile("" ::: "memory");                                       \
        __builtin_amdgcn_s_setprio(1);                                       \
        MFMAS(p_, cfh, cfl);                                                 \
        __builtin_amdgcn_s_setprio(0);                                       \
        __builtin_amdgcn_s_waitcnt(WT_VM4);                                  \
        asm volatile("" ::: "memory");                                       \
        __builtin_amdgcn_s_barrier();                                        \
        asm volatile("" ::: "memory");                                       \
        cfh = *(const bf16x8*)(ldsRd + (((p_) ^ 1)) * 4096);                 \
        cfl = *(const bf16x8*)(ldsRd + (((p_) ^ 1)) * 4096 + 1024);          \
    }

    // Prologue: stage kb=0 into buf0, A(0) into slot0.
    STAGE(0, 0);
    LOADA(0, 0);
    __builtin_amdgcn_s_waitcnt(WT_VM4);   // stage(0) done (A(0) 4 younger)
    asm volatile("" ::: "memory");
    __builtin_amdgcn_s_barrier();
    asm volatile("" ::: "memory");
    bf16x8 cfh = *(const bf16x8*)(ldsRd);
    bf16x8 cfl = *(const bf16x8*)(ldsRd + 1024);

    for (int kb = 0; kb < NKB - 2; kb += 2) {
        STEP(kb + 0, 0);
        STEP(kb + 1, 1);
    }
    STEP(NKB - 2, 0);                     // stages+loads NKB-1; reads frags
    {   // final step kb = NKB-1 (parity 1): nothing left to issue
        __builtin_amdgcn_s_waitcnt(WT_VM0_LG0);
        asm volatile("" ::: "memory");
        __builtin_amdgcn_s_setprio(1);
        MFMAS(1, cfh, cfl);
        __builtin_amdgcn_s_setprio(0);
    }

#undef STEP
#undef MFMAS
#undef EXPANDF
#undef LOADA
#undef STAGE

    // --- LIF epilogue: t-scan in registers (XLA-exact arithmetic) ---
    const float bv = bias[n0 + wave_n + l31];
    f32x16 vmem;
#pragma unroll
    for (int rr = 0; rr < 16; ++rr) vmem[rr] = 0.0f;
    uint64_t bits = 0ull;
    unsigned short* myt = &sh[wid][0];          // [row][kb][t] = [32][2][4]

    const int NKBo = N >> 4;
    const int kbase = (n0 + wave_n) >> 4;

    for (int t = 0; t < TSTEPS; ++t) {
#pragma unroll
        for (int rr = 0; rr < 16; ++rr) {
            float y = __fadd_rn(acc[t][rr], bv);
            float vv = vmem[rr];
            vv = __fadd_rn(vv, __fmul_rn(__fsub_rn(y, vv), 0.5f));
            bool sp = (vv >= 1.0f);
            vmem[rr] = sp ? 0.0f : vv;
            if (LAST) {
                bits |= sp ? (1ull << (rr * 4 + t)) : 0ull;
            } else {
                unsigned long long b = __ballot(sp);
                if (l31 == 0) {
                    uint32_t hb = (uint32_t)(b >> (half * 32));
                    int rowi = (rr & 3) + 8 * (rr >> 2) + 4 * half;
                    myt[(rowi * 2 + 0) * 4 + t] = (unsigned short)hb;
                    myt[(rowi * 2 + 1) * 4 + t] = (unsigned short)(hb >> 16);
                }
            }
        }
    }

    if (LAST) {
        // Out writes + fused mean-over-L. All values multiples of 2^-11,
        // totals <= 1 -> fp32 atomics exact and order-independent.
        float psum = 0.0f;
#pragma unroll
        for (int rr = 0; rr < 16; ++rr) {
            int m_r = (rr & 3) + 8 * (rr >> 2) + 4 * half;
            int m = m0 + wave_m + m_r;
            int n = n0 + wave_n + l31;
            int cnt = __popc((unsigned)((bits >> (rr * 4)) & 0xFull));
            float val = 0.25f * (float)cnt;
            Out[(size_t)m * N + n] = val;
            psum += val;                       // exact: multiples of 0.25
        }
        // combine the two halves (same n, other 16 m's of the 32-row blk)
        psum += __shfl_xor(psum, 32, 64);
        if (half == 0) {
            float* out2 = Out + (size_t)M * N;
            int b = m0 >> 9;                   // m0 multiple of 64; L = 512
            int n = n0 + wave_n + l31;
            atomicAdd(out2 + (size_t)b * N + n, psum * (1.0f / 512.0f));
        }
    } else {
        // Emit next-stage A bytes: 0x00 / 0x3F.
        const ushort4v pk = *(const ushort4v*)&myt[(l31 * 2 + half) * 4];
#pragma unroll
        for (int t = 0; t < TSTEPS; ++t) {
            uint32_t m16 = pk[t];
            uint4 o;
            o.x = (((m16      ) & 0xFu) * 0x00204081u & 0x01010101u) * 0x3Fu;
            o.y = (((m16 >>  4) & 0xFu) * 0x00204081u & 0x01010101u) * 0x3Fu;
            o.z = (((m16 >>  8) & 0xFu) * 0x00204081u & 0x01010101u) * 0x3Fu;
            o.w = (((m16 >> 12) & 0xFu) * 0x00204081u & 0x01010101u) * 0x3Fu;
            *(uint4*)(Sbytes + ((((size_t)m_blk * NKBo + kbase + half) * 4 + t)
                                * 32 + l31) * 16) = o;
        }
    }
}

// ---------------------------------------------------------------------------
// Zero out2 (graph-capture-safe replacement for hipMemsetAsync).
// ---------------------------------------------------------------------------
__global__ void zero_out2(float* __restrict__ out2, int n)
{
    int i = blockIdx.x * blockDim.x + threadIdx.x;
    if (i < n) out2[i] = 0.0f;
}

// ---------------------------------------------------------------------------
extern "C" void kernel_launch(void* const* d_in, const int* in_sizes, int n_in,
                              void* d_out, int out_size, void* d_ws, size_t ws_size,
                              hipStream_t stream)
{
    const float* inputs  = (const float*)d_in[0];  // [16,512,128]
    const float* enc_W   = (const float*)d_in[1];  // [128,1024]
    const float* enc_b   = (const float*)d_in[2];  // [1024]
    const float* W_cells = (const float*)d_in[3];  // [2,1024,1024]
    const float* b_cells = (const float*)d_in[4];  // [2,1024]

    const int B = 16, L = 512, C = 128, D = 1024;
    const int M = B * L;  // 8192

    // ws: s1 i8 4MB | W1h/l 0.5MB | W2h/l 4MB | W3h/l 4MB | h0 32MB | h1 32MB
    char* ws = (char*)d_ws;
    size_t off = 0;
    uint8_t* s1 = (uint8_t*)(ws + off);
    off += (size_t)(M / 32) * (C / 16) * 4 * 32 * 16;
    bf16_t* W1h = (bf16_t*)(ws + off); off += (size_t)C * D * 2;
    bf16_t* W1l = (bf16_t*)(ws + off); off += (size_t)C * D * 2;
    bf16_t* W2h = (bf16_t*)(ws + off); off += (size_t)D * D * 2;
    bf16_t* W2l = (bf16_t*)(ws + off); off += (size_t)D * D * 2;
    bf16_t* W3h = (bf16_t*)(ws + off); off += (size_t)D * D * 2;
    bf16_t* W3l = (bf16_t*)(ws + off); off += (size_t)D * D * 2;
    uint8_t* h0 = (uint8_t*)(ws + off);
    off += (size_t)(M / 32) * (D / 16) * 4 * 32 * 16;
    uint8_t* h1 = (uint8_t*)(ws + off);

    float* out  = (float*)d_out;          // [M, D]
    float* out2 = out + (size_t)M * D;    // [B, D]

    split_transpose_all<<<dim3(32, 32, 3), 256, 0, stream>>>(
        enc_W, W_cells, W1h, W1l, W2h, W2l, W3h, W3l);

    spike_encode_i8<<<256, 256, 0, stream>>>(inputs, (uint4*)s1);

    zero_out2<<<(B * D + 255) / 256, 256, 0, stream>>>(out2, B * D);

    const int nblocks = (M / 64) * (D / 64);   // 2048
    gemm_lif_mfma<128, false><<<nblocks, 256, 0, stream>>>(
        s1, W1h, W1l, enc_b, h0, nullptr, M, D);
    gemm_lif_mfma<1024, false><<<nblocks, 256, 0, stream>>>(
        h0, W2h, W2l, b_cells, h1, nullptr, M, D);
    gemm_lif_mfma<1024, true><<<nblocks, 256, 0, stream>>>(
        h1, W3h, W3l, b_cells + D, nullptr, out, M, D);
}

// Round 9
// 303.200 us; speedup vs baseline: 1.1598x; 1.0411x over previous
//
#include <hip/hip_runtime.h>
#include <hip/hip_bf16.h>
#include <stdint.h>

#define TSTEPS 4

typedef __bf16 bf16_t;
typedef __attribute__((ext_vector_type(8))) __bf16 bf16x8;
typedef __attribute__((ext_vector_type(16))) float f32x16;
typedef __attribute__((ext_vector_type(4))) unsigned short ushort4v;

union frag_u { bf16x8 v; uint32_t d[4]; unsigned short u[8]; };

// gfx9 s_waitcnt imm: vm [3:0]|[15:14]; exp [6:4]; lgkm [11:8].
#define WT_VM5      0xF75   // vmcnt(5)
#define WT_VM5_LG0  0x075   // vmcnt(5) lgkmcnt(0)
#define WT_VM4_LG0  0x074   // vmcnt(4) lgkmcnt(0)
#define WT_VM0_LG0  0x070   // full drain (tail)

// ---------------------------------------------------------------------------
// R25 = R24 minus setprio (bundled-negative), plus DEPTH-2 B-staging:
// 4-buffer LDS ring, stage kb+2 in step kb. In R22/R24 the stage for kb+1
// was issued and waited within the SAME step (~150cy of cover vs ~250cy L2
// latency) -> every step all 4 waves stalled at the barrier for the slowest
// stage; ~81K all-stop cyc/CU = the 28% gap (MFMA 45% + VALU 27% + 28%).
// Now stage(kb+1) is drained by the vmcnt(5) one FULL step (~560cy) after
// issue, and the barrier waits on no fresh memory. A loads keep their
// existing one-step slack. Buffer-reuse: buf[(kb+2)&3] holds kb-2's data,
// consumed and lgkm-drained two barriers before the overwrite is issued.
// Fused mean-over-L in LAST epilogue kept (R24 win, ~8us).
// Spike bytes 0x3F -> v_perm high-byte = bf16 0.5; B pre-doubled (exact
// exponent bump) so products are bitwise 1.0*w (R19/R21/R22-proven).
// A layout: [m_blk32][kb16][t][row0..31][16 bytes], byte = 0x00 / 0x3F.
// B-frag layout: packet ((n>>5)*NKB + (k>>4))*512 + ((n&31)+32*((k>>3)&1))*8
// + (k&7), bf16, value = 2*w_hi / 2*w_lo.
// ---------------------------------------------------------------------------

// ---------------------------------------------------------------------------
// Stage 1: input LIF encoder -> spike 0x3F bytes. C=128. XLA-exact LIF.
// ---------------------------------------------------------------------------
__global__ void spike_encode_i8(const float* __restrict__ x,
                                uint4* __restrict__ s1)
{
    const int C = 128;
    int tid = blockIdx.x * blockDim.x + threadIdx.x;  // 65536 = 256*8*32
    int row = tid & 31;
    int kb  = (tid >> 5) & 7;
    int m_blk = tid >> 8;
    int m = m_blk * 32 + row;
    const float* px = x + (size_t)m * C + kb * 16;
    float xv[16];
#pragma unroll
    for (int j = 0; j < 16; j += 4) {
        float4 t4 = *(const float4*)(px + j);
        xv[j] = t4.x; xv[j+1] = t4.y; xv[j+2] = t4.z; xv[j+3] = t4.w;
    }
    float v[16];
#pragma unroll
    for (int j = 0; j < 16; ++j) v[j] = 0.0f;
#pragma unroll
    for (int t = 0; t < TSTEPS; ++t) {
        uint32_t dw[4] = {0u, 0u, 0u, 0u};
#pragma unroll
        for (int j = 0; j < 16; ++j) {
            float vv = __fadd_rn(v[j], __fmul_rn(__fsub_rn(xv[j], v[j]), 0.5f));
            bool sp = (vv >= 1.0f);
            dw[j >> 2] |= sp ? (0x3Fu << ((j & 3) * 8)) : 0u;
            v[j] = sp ? 0.0f : vv;
        }
        uint4 o; o.x = dw[0]; o.y = dw[1]; o.z = dw[2]; o.w = dw[3];
        s1[((size_t)(m_blk * 8 + kb) * 4 + t) * 32 + row] = o;
    }
}

// ---------------------------------------------------------------------------
// Weight prep: W [K][N] fp32 -> 2*hi / 2*lo bf16 split in B-frag layout.
// ---------------------------------------------------------------------------
__global__ void split_transpose_all(const float* __restrict__ enc_W,
                                    const float* __restrict__ W_cells,
                                    bf16_t* __restrict__ W1h, bf16_t* __restrict__ W1l,
                                    bf16_t* __restrict__ W2h, bf16_t* __restrict__ W2l,
                                    bf16_t* __restrict__ W3h, bf16_t* __restrict__ W3l)
{
    const int N = 1024;
    const float* W;
    bf16_t *hi, *lo;
    int K;
    if (blockIdx.z == 0) {
        if (blockIdx.x >= 4) return;
        W = enc_W; hi = W1h; lo = W1l; K = 128;
    } else if (blockIdx.z == 1) {
        W = W_cells; hi = W2h; lo = W2l; K = 1024;
    } else {
        W = W_cells + (size_t)1024 * 1024; hi = W3h; lo = W3l; K = 1024;
    }
    const int NKB = K >> 4;
    __shared__ float tile[32][33];
    int k0 = blockIdx.x * 32, n0 = blockIdx.y * 32;
    int tx = threadIdx.x & 31, ty = threadIdx.x >> 5;
    for (int kk = ty; kk < 32; kk += 8)
        tile[kk][tx] = W[(size_t)(k0 + kk) * N + n0 + tx];
    __syncthreads();

    const int nn = tx;
    const int oc = ty;            // 0..7
    const int o2 = oc & 3;        // k-octet
    const bool isLo = (oc >> 2) != 0;
    const int kblk = (k0 >> 4) + (o2 >> 1);
    const int lane_in_packet = nn + 32 * (o2 & 1);

    frag_u f;
#pragma unroll
    for (int j = 0; j < 8; ++j) {
        float wv = tile[o2 * 8 + j][nn];
        bf16_t h = (bf16_t)wv;                          // original hi rounding
        bf16_t l = (bf16_t)(wv - (float)h);             // original lo rounding
        f.v[j] = isLo ? (bf16_t)(2.0f * (float)l)       // exact doubling
                      : (bf16_t)(2.0f * (float)h);
    }
    bf16_t* dst = (isLo ? lo : hi)
        + ((size_t)((n0 + nn) >> 5) * NKB + kblk) * 512 + lane_in_packet * 8;
    *(bf16x8*)dst = f.v;
}

// ---------------------------------------------------------------------------
// Fused MFMA GEMM + multistep LIF. R25: depth-2 LDS staging (4-buf ring),
// hoisted frag reads, counted waits, fused mean (LAST).
// ---------------------------------------------------------------------------
template <int K, bool LAST>
__global__ __launch_bounds__(256, 4)
void gemm_lif_mfma(const uint8_t* __restrict__ Abytes,
                   const bf16_t* __restrict__ Bh,
                   const bf16_t* __restrict__ Bl,
                   const float* __restrict__ bias,
                   uint8_t* __restrict__ Sbytes,
                   float* __restrict__ Out,
                   int M, int N)
{
    constexpr int NKB = K >> 4;                 // 8 or 64 (even)
    __shared__ __align__(16) uint8_t ldsB[4][4096];      // 4-buf B ring
    __shared__ __align__(8) unsigned short sh[4][256];   // epilogue, per-wave

    const int tid = threadIdx.x;
    const int lane = tid & 63;
    const int wid = tid >> 6;
    const int l31 = lane & 31;
    const int half = lane >> 5;

    // XCD-locality swizzle (R18): XCD x owns m_t in [x*16, x*16+16);
    // walk nh(2) x mloc(16) x n8(8). Bijective.
    const int bid = blockIdx.x;
    const int xcd = bid & 7;
    const int j   = bid >> 3;                   // 0..255
    const int nh   = j >> 7;                    // 0..1
    const int r    = j & 127;
    const int mloc = r >> 3;                    // 0..15
    const int n_t  = nh * 8 + (r & 7);          // 0..15
    const int m_t  = xcd * 16 + mloc;           // 0..127

    const int m0 = m_t * 64, n0 = n_t * 64;
    const int wave_m = (wid & 1) * 32;
    const int wave_n = (wid >> 1) * 32;
    const int m_blk = (m0 + wave_m) >> 5;

    const uint8_t* pA = Abytes + (size_t)m_blk * NKB * 4 * 512 + l31 * 16 + half * 8;

    // B staging: wave wid stages chunk wid = (n_local = wid>>1, plane = wid&1)
    // at LDS offset buf*4096 + wid*1024. Source: the 1KB lane-linear packet.
    const uint8_t* stage_src = (const uint8_t*)(((wid & 1) ? Bl : Bh)
        + (size_t)((n0 >> 5) + (wid >> 1)) * NKB * 512) + (lane << 4);
    uint8_t* ldsStage = &ldsB[0][0] + (wid << 10);
    // Consumer: wave wid reads n_local = wid>>1: hi at +0, lo at +1024.
    const uint8_t* ldsRd = &ldsB[0][0] + ((wid >> 1) << 11) + (lane << 4);

    f32x16 acc[TSTEPS];
#pragma unroll
    for (int t = 0; t < TSTEPS; ++t)
        for (int rr = 0; rr < 16; ++rr) acc[t][rr] = 0.0f;

    uint2 fm[2][4];

#define STAGE(kb_, buf_)                                                      \
    __builtin_amdgcn_global_load_lds(                                         \
        (const __attribute__((address_space(1))) uint32_t*)                   \
            (stage_src + (size_t)(kb_) * 1024),                               \
        (__attribute__((address_space(3))) uint32_t*)                         \
            (ldsStage + ((buf_) << 12)),                                      \
        16, 0, 0);

#define LOADA(kb_, s_) {                                                     \
        fm[s_][0] = *(const uint2*)(pA + ((size_t)(kb_) * 4 + 0) * 512);     \
        fm[s_][1] = *(const uint2*)(pA + ((size_t)(kb_) * 4 + 1) * 512);     \
        fm[s_][2] = *(const uint2*)(pA + ((size_t)(kb_) * 4 + 2) * 512);     \
        fm[s_][3] = *(const uint2*)(pA + ((size_t)(kb_) * 4 + 3) * 512);     \
    }

// byte 0x3F -> high byte of each 16-bit half = 0x3F00 = bf16 0.5 (1 perm/dw)
#define EXPANDF(a_, f_) {                                                    \
        (f_).d[0] = __builtin_amdgcn_perm((a_).x, 0u, 0x05000400u);          \
        (f_).d[1] = __builtin_amdgcn_perm((a_).x, 0u, 0x07000600u);          \
        (f_).d[2] = __builtin_amdgcn_perm((a_).y, 0u, 0x05000400u);          \
        (f_).d[3] = __builtin_amdgcn_perm((a_).y, 0u, 0x07000600u);          \
    }

#define MFMAS(s_, fhv_, flv_) {                                              \
        frag_u af0, af1, af2, af3;                                           \
        EXPANDF(fm[s_][0], af0);                                             \
        EXPANDF(fm[s_][1], af1);                                             \
        EXPANDF(fm[s_][2], af2);                                             \
        EXPANDF(fm[s_][3], af3);                                             \
        acc[0] = __builtin_amdgcn_mfma_f32_32x32x16_bf16(af0.v, fhv_, acc[0], 0, 0, 0); \
        acc[1] = __builtin_amdgcn_mfma_f32_32x32x16_bf16(af1.v, fhv_, acc[1], 0, 0, 0); \
        acc[2] = __builtin_amdgcn_mfma_f32_32x32x16_bf16(af2.v, fhv_, acc[2], 0, 0, 0); \
        acc[3] = __builtin_amdgcn_mfma_f32_32x32x16_bf16(af3.v, fhv_, acc[3], 0, 0, 0); \
        acc[0] = __builtin_amdgcn_mfma_f32_32x32x16_bf16(af0.v, flv_, acc[0], 0, 0, 0); \
        acc[1] = __builtin_amdgcn_mfma_f32_32x32x16_bf16(af1.v, flv_, acc[1], 0, 0, 0); \
        acc[2] = __builtin_amdgcn_mfma_f32_32x32x16_bf16(af2.v, flv_, acc[2], 0, 0, 0); \
        acc[3] = __builtin_amdgcn_mfma_f32_32x32x16_bf16(af3.v, flv_, acc[3], 0, 0, 0); \
    }

// Step kb_ (parity p_): frags for kb_ already in cfh/cfl (read after the
// previous barrier). Issue stage(kb_+2) into ring buf (kb_+2)&3 and A(kb_+1).
// vmcnt(5)+lgkm(0): outstanding = stage(kb_+2) + A(kb_+1)x4 -> drains
// A(kb_) AND stage(kb_+1) (issued one full step ago: latency covered).
// Barrier then publishes stage(kb_+1); read its frags after.
// Ring-reuse safety: buf (kb_+2)&3 held kb_-2's data, ds-read-drained two
// barriers before this STAGE is issued.
#define STEPD(kb_, p_) {                                                     \
        STAGE((kb_) + 2, ((kb_) + 2) & 3);                                   \
        LOADA((kb_) + 1, (p_) ^ 1);                                          \
        __builtin_amdgcn_s_waitcnt(WT_VM5_LG0);                              \
        asm volatile("" ::: "memory");                                       \
        MFMAS(p_, cfh, cfl);                                                 \
        __builtin_amdgcn_s_barrier();                                        \
        asm volatile("" ::: "memory");                                       \
        cfh = *(const bf16x8*)(ldsRd + ((((kb_) + 1) & 3) << 12));           \
        cfl = *(const bf16x8*)(ldsRd + ((((kb_) + 1) & 3) << 12) + 1024);    \
    }

    // Prologue: stage kb 0,1 into bufs 0,1; A(0) into slot 0.
    STAGE(0, 0);
    STAGE(1, 1);
    LOADA(0, 0);
    __builtin_amdgcn_s_waitcnt(WT_VM5);   // drains stage(0) (5 younger remain)
    asm volatile("" ::: "memory");
    __builtin_amdgcn_s_barrier();
    asm volatile("" ::: "memory");
    bf16x8 cfh = *(const bf16x8*)(ldsRd);
    bf16x8 cfl = *(const bf16x8*)(ldsRd + 1024);

    for (int kb = 0; kb < NKB - 2; kb += 2) {
        STEPD(kb + 0, 0);
        STEPD(kb + 1, 1);
    }
    // Step NKB-2 (parity 0): nothing more to stage.
    LOADA(NKB - 1, 1);
    __builtin_amdgcn_s_waitcnt(WT_VM4_LG0);  // drains A(NKB-2)+stage(NKB-1)
    asm volatile("" ::: "memory");
    MFMAS(0, cfh, cfl);
    __builtin_amdgcn_s_barrier();
    asm volatile("" ::: "memory");
    cfh = *(const bf16x8*)(ldsRd + (((NKB - 1) & 3) << 12));
    cfl = *(const bf16x8*)(ldsRd + (((NKB - 1) & 3) << 12) + 1024);
    // Step NKB-1 (parity 1): full drain.
    __builtin_amdgcn_s_waitcnt(WT_VM0_LG0);
    asm volatile("" ::: "memory");
    MFMAS(1, cfh, cfl);

#undef STEPD
#undef MFMAS
#undef EXPANDF
#undef LOADA
#undef STAGE

    // --- LIF epilogue: t-scan in registers (XLA-exact arithmetic) ---
    const float bv = bias[n0 + wave_n + l31];
    f32x16 vmem;
#pragma unroll
    for (int rr = 0; rr < 16; ++rr) vmem[rr] = 0.0f;
    uint64_t bits = 0ull;
    unsigned short* myt = &sh[wid][0];          // [row][kb][t] = [32][2][4]

    const int NKBo = N >> 4;
    const int kbase = (n0 + wave_n) >> 4;

    for (int t = 0; t < TSTEPS; ++t) {
#pragma unroll
        for (int rr = 0; rr < 16; ++rr) {
            float y = __fadd_rn(acc[t][rr], bv);
            float vv = vmem[rr];
            vv = __fadd_rn(vv, __fmul_rn(__fsub_rn(y, vv), 0.5f));
            bool sp = (vv >= 1.0f);
            vmem[rr] = sp ? 0.0f : vv;
            if (LAST) {
                bits |= sp ? (1ull << (rr * 4 + t)) : 0ull;
            } else {
                unsigned long long b = __ballot(sp);
                if (l31 == 0) {
                    uint32_t hb = (uint32_t)(b >> (half * 32));
                    int rowi = (rr & 3) + 8 * (rr >> 2) + 4 * half;
                    myt[(rowi * 2 + 0) * 4 + t] = (unsigned short)hb;
                    myt[(rowi * 2 + 1) * 4 + t] = (unsigned short)(hb >> 16);
                }
            }
        }
    }

    if (LAST) {
        // Out writes + fused mean-over-L. All values multiples of 2^-11,
        // totals <= 1 -> fp32 atomics exact and order-independent.
        float psum = 0.0f;
#pragma unroll
        for (int rr = 0; rr < 16; ++rr) {
            int m_r = (rr & 3) + 8 * (rr >> 2) + 4 * half;
            int m = m0 + wave_m + m_r;
            int n = n0 + wave_n + l31;
            int cnt = __popc((unsigned)((bits >> (rr * 4)) & 0xFull));
            float val = 0.25f * (float)cnt;
            Out[(size_t)m * N + n] = val;
            psum += val;                       // exact: multiples of 0.25
        }
        // combine the two halves (same n, other 16 m's of the 32-row blk)
        psum += __shfl_xor(psum, 32, 64);
        if (half == 0) {
            float* out2 = Out + (size_t)M * N;
            int b = m0 >> 9;                   // m0 multiple of 64; L = 512
            int n = n0 + wave_n + l31;
            atomicAdd(out2 + (size_t)b * N + n, psum * (1.0f / 512.0f));
        }
    } else {
        // Emit next-stage A bytes: 0x00 / 0x3F.
        const ushort4v pk = *(const ushort4v*)&myt[(l31 * 2 + half) * 4];
#pragma unroll
        for (int t = 0; t < TSTEPS; ++t) {
            uint32_t m16 = pk[t];
            uint4 o;
            o.x = (((m16      ) & 0xFu) * 0x00204081u & 0x01010101u) * 0x3Fu;
            o.y = (((m16 >>  4) & 0xFu) * 0x00204081u & 0x01010101u) * 0x3Fu;
            o.z = (((m16 >>  8) & 0xFu) * 0x00204081u & 0x01010101u) * 0x3Fu;
            o.w = (((m16 >> 12) & 0xFu) * 0x00204081u & 0x01010101u) * 0x3Fu;
            *(uint4*)(Sbytes + ((((size_t)m_blk * NKBo + kbase + half) * 4 + t)
                                * 32 + l31) * 16) = o;
        }
    }
}

// ---------------------------------------------------------------------------
// Zero out2 (graph-capture-safe replacement for hipMemsetAsync).
// ---------------------------------------------------------------------------
__global__ void zero_out2(float* __restrict__ out2, int n)
{
    int i = blockIdx.x * blockDim.x + threadIdx.x;
    if (i < n) out2[i] = 0.0f;
}

// ---------------------------------------------------------------------------
extern "C" void kernel_launch(void* const* d_in, const int* in_sizes, int n_in,
                              void* d_out, int out_size, void* d_ws, size_t ws_size,
                              hipStream_t stream)
{
    const float* inputs  = (const float*)d_in[0];  // [16,512,128]
    const float* enc_W   = (const float*)d_in[1];  // [128,1024]
    const float* enc_b   = (const float*)d_in[2];  // [1024]
    const float* W_cells = (const float*)d_in[3];  // [2,1024,1024]
    const float* b_cells = (const float*)d_in[4];  // [2,1024]

    const int B = 16, L = 512, C = 128, D = 1024;
    const int M = B * L;  // 8192

    // ws: s1 i8 4MB | W1h/l 0.5MB | W2h/l 4MB | W3h/l 4MB | h0 32MB | h1 32MB
    char* ws = (char*)d_ws;
    size_t off = 0;
    uint8_t* s1 = (uint8_t*)(ws + off);
    off += (size_t)(M / 32) * (C / 16) * 4 * 32 * 16;
    bf16_t* W1h = (bf16_t*)(ws + off); off += (size_t)C * D * 2;
    bf16_t* W1l = (bf16_t*)(ws + off); off += (size_t)C * D * 2;
    bf16_t* W2h = (bf16_t*)(ws + off); off += (size_t)D * D * 2;
    bf16_t* W2l = (bf16_t*)(ws + off); off += (size_t)D * D * 2;
    bf16_t* W3h = (bf16_t*)(ws + off); off += (size_t)D * D * 2;
    bf16_t* W3l = (bf16_t*)(ws + off); off += (size_t)D * D * 2;
    uint8_t* h0 = (uint8_t*)(ws + off);
    off += (size_t)(M / 32) * (D / 16) * 4 * 32 * 16;
    uint8_t* h1 = (uint8_t*)(ws + off);

    float* out  = (float*)d_out;          // [M, D]
    float* out2 = out + (size_t)M * D;    // [B, D]

    split_transpose_all<<<dim3(32, 32, 3), 256, 0, stream>>>(
        enc_W, W_cells, W1h, W1l, W2h, W2l, W3h, W3l);

    spike_encode_i8<<<256, 256, 0, stream>>>(inputs, (uint4*)s1);

    zero_out2<<<(B * D + 255) / 256, 256, 0, stream>>>(out2, B * D);

    const int nblocks = (M / 64) * (D / 64);   // 2048
    gemm_lif_mfma<128, false><<<nblocks, 256, 0, stream>>>(
        s1, W1h, W1l, enc_b, h0, nullptr, M, D);
    gemm_lif_mfma<1024, false><<<nblocks, 256, 0, stream>>>(
        h0, W2h, W2l, b_cells, h1, nullptr, M, D);
    gemm_lif_mfma<1024, true><<<nblocks, 256, 0, stream>>>(
        h1, W3h, W3l, b_cells + D, nullptr, out, M, D);
}